// Round 13
// baseline (267.774 us; speedup 1.0000x reference)
//
#include <hip/hip_runtime.h>
#include <hip/hip_bf16.h>
#include <hip/hip_cooperative_groups.h>

namespace cg = cooperative_groups;

#define B_ 8
#define E_ 2048
#define N_ 2048
#define F_ 128

#define BM 64      // hyperedge rows per block (4 m-tiles of 16)
#define MT 4       // m-tiles
#define BK 128     // K chunk (elements) -> 16 iterations
#define MP 136     // msg LDS pitch

using bf16x8 = __bf16 __attribute__((ext_vector_type(8)));
using fx4    = float __attribute__((ext_vector_type(4)));

// One cooperative kernel: phase0 = block-owned node-tile transpose (+W cvt),
// grid sync, then fused adj-stream + bitpack + GEMM1 + norm + GEMM2.
__global__ __launch_bounds__(256, 1) void v2h_coop(const float* __restrict__ node,
                                                   const float* __restrict__ adj,
                                                   const float* __restrict__ W,
                                                   const float* __restrict__ bias,
                                                   __bf16* __restrict__ nodeT,
                                                   __bf16* __restrict__ Wb,
                                                   float* __restrict__ out) {
    __shared__ __align__(16) __bf16 Bs[2][128][BK];     // 64 KB, swizzled DMA layout
    __shared__ __align__(16) unsigned Abits[2][BM][4];  // 2 KB, dbuf bit tiles
    __shared__ float normS[BM];                         // 256 B
    __shared__ __align__(16) __bf16 Ms[BM * MP];        // 17.4 KB

    const int t    = threadIdx.x;
    const int bid  = blockIdx.x;
    const int b    = bid & 7;            // batch -> XCD L2 locality
    const int j    = bid >> 3;           // 0..31: e-tile AND owned n-tile
    const int e0   = j * BM;
    const int w    = t >> 6;             // wave id = f-group (32 cols)
    const int lane = t & 63;
    const int l15  = lane & 15;
    const int quad = lane >> 4;

    // ---- phase 0: transpose own node tile (n in [j*64, j*64+64)) ----
    {
        const int f = t & 127;
#pragma unroll
        for (int u = 0; u < 2; ++u) {
            const int nb = j * 64 + u * 32 + (t >> 7) * 16;
            const float* src = node + ((size_t)b * N_ + nb) * F_ + f;
            __bf16 h[16];
#pragma unroll
            for (int i = 0; i < 16; ++i)
                h[i] = (__bf16)src[(size_t)i * F_];
            __bf16* dst = nodeT + ((size_t)b * F_ + f) * N_ + nb;
            *(uint4*)&dst[0] = *(const uint4*)&h[0];
            *(uint4*)&dst[8] = *(const uint4*)&h[8];
        }
    }
    if (bid < 16) {   // W f32 -> bf16 (16 blocks x 1024 x 4 floats)
        int idx = bid * 256 + t;
        float4 v = *(const float4*)&W[idx * 4];
        __bf16 o[4] = {(__bf16)v.x, (__bf16)v.y, (__bf16)v.z, (__bf16)v.w};
        *(uint2*)&Wb[idx * 4] = *(const uint2*)o;
    }
    cg::this_grid().sync();              // nodeT + Wb globally ready

    // ---- adj stream: row ar = t>>2 (0..63), k-span acs*32 (32 floats) ----
    const int ar  = t >> 2;
    const int acs = t & 3;
    const float* aRow = adj + ((size_t)b * E_ + e0 + ar) * N_ + acs * 32;
    const __bf16* nTB = nodeT + (size_t)b * F_ * N_;

    auto issue_dma = [&](int k0, int buf) {
#pragma unroll
        for (int p = 0; p < 8; ++p) {
            int idx = t + 256 * p;               // 0..2047 granules (16B)
            int f   = idx >> 4;                  // 0..127
            int sl  = idx & 15;                  // LDS slot in row
            int g   = sl ^ (f & 15);             // source granule (XOR swizzle)
            const __bf16* src = nTB + (size_t)f * N_ + k0 + g * 8;
            __bf16* dst = &Bs[buf][0][0] + (size_t)(w * 64 + 256 * p) * 8; // wave-uniform
            __builtin_amdgcn_global_load_lds(
                (const __attribute__((address_space(1))) void*)src,
                (__attribute__((address_space(3))) void*)dst, 16, 0, 0);
        }
    };

    auto cvt32 = [](const float4* a) -> unsigned {
        unsigned m = 0;
#pragma unroll
        for (int i = 0; i < 8; ++i) {
            m |= (a[i].x == -1.f) ? (1u << (4 * i))     : 0u;
            m |= (a[i].y == -1.f) ? (1u << (4 * i + 1)) : 0u;
            m |= (a[i].z == -1.f) ? (1u << (4 * i + 2)) : 0u;
            m |= (a[i].w == -1.f) ? (1u << (4 * i + 3)) : 0u;
        }
        return m;
    };

    auto unpack = [](unsigned byte) -> bf16x8 {
        union { unsigned u[4]; bf16x8 v; } r;
        r.u[0] = ((byte &   1u) ? 0x3F80u : 0u) | ((byte &   2u) ? 0x3F800000u : 0u);
        r.u[1] = ((byte &   4u) ? 0x3F80u : 0u) | ((byte &   8u) ? 0x3F800000u : 0u);
        r.u[2] = ((byte &  16u) ? 0x3F80u : 0u) | ((byte &  32u) ? 0x3F800000u : 0u);
        r.u[3] = ((byte &  64u) ? 0x3F80u : 0u) | ((byte & 128u) ? 0x3F800000u : 0u);
        return r.v;
    };

    fx4 acc[MT][2] = {};
    int cnt = 0;
    float4 aR[8];

    // ---- prologue: tile 0 -> Abits[0]; DMA(0); tile 1 regs in flight ----
#pragma unroll
    for (int i = 0; i < 8; ++i) aR[i] = *(const float4*)(aRow + 4 * i);
    issue_dma(0, 0);
    {
        unsigned bits = cvt32(aR);
        Abits[0][ar][acs] = bits;
        cnt += __popc(bits);
    }
#pragma unroll
    for (int i = 0; i < 8; ++i) aR[i] = *(const float4*)(aRow + BK + 4 * i);

#pragma unroll
    for (int m = 0; m < 16; ++m) {
        const int buf = m & 1;
        __syncthreads();   // drains B-DMA(m) + adj regs; Abits[buf] visible

        if (m < 15) {
            issue_dma((m + 1) * BK, buf ^ 1);
            unsigned bits = cvt32(aR);           // tile m+1
            Abits[buf ^ 1][ar][acs] = bits;
            cnt += __popc(bits);
        }
        if (m < 14) {
            const float* ap = aRow + (m + 2) * BK;
#pragma unroll
            for (int i = 0; i < 8; ++i) aR[i] = *(const float4*)(ap + 4 * i);
        }

        // ---- A bit rows (one uint4 per m-tile) ----
        uint4 va[MT];
#pragma unroll
        for (int mt = 0; mt < MT; ++mt)
            va[mt] = *(const uint4*)&Abits[buf][mt * 16 + l15][0];

        // ---- 4 k-steps of 32: af from byte quad of va[s]; B at slot (s*4+quad)^l15 ----
#pragma unroll
        for (int s = 0; s < 4; ++s) {
            bf16x8 af[MT];
            const unsigned* vp0 = (const unsigned*)&va[0];
            const unsigned* vp1 = (const unsigned*)&va[1];
            const unsigned* vp2 = (const unsigned*)&va[2];
            const unsigned* vp3 = (const unsigned*)&va[3];
            af[0] = unpack((vp0[s] >> (8 * quad)) & 255u);
            af[1] = unpack((vp1[s] >> (8 * quad)) & 255u);
            af[2] = unpack((vp2[s] >> (8 * quad)) & 255u);
            af[3] = unpack((vp3[s] >> (8 * quad)) & 255u);
            const int slot = (s * 4 + quad) ^ l15;
#pragma unroll
            for (int ft = 0; ft < 2; ++ft) {
                int f = w * 32 + ft * 16 + l15;
                bf16x8 bf = *(const bf16x8*)&Bs[buf][f][slot * 8];
#pragma unroll
                for (int mt = 0; mt < MT; ++mt)
                    acc[mt][ft] = __builtin_amdgcn_mfma_f32_16x16x32_bf16(af[mt], bf, acc[mt][ft], 0, 0, 0);
            }
        }
    }

    // ---- norm: reduce count over the 4 k-quarter threads of each row ----
    {
        float c = (float)cnt;
        c += __shfl_xor(c, 1);
        c += __shfl_xor(c, 2);
        if (acs == 0)
            normS[ar] = 1.f / fmaxf(c, 1.f);
    }
    __syncthreads();

    // ---- scale by 1/count, write msg bf16 to LDS in [m][f] layout ----
    const int rbase = quad * 4;
    float4 rn[MT];
#pragma unroll
    for (int mt = 0; mt < MT; ++mt)
        rn[mt] = *(const float4*)&normS[mt * 16 + rbase];

#pragma unroll
    for (int ft = 0; ft < 2; ++ft) {
        int fcol = w * 32 + ft * 16 + l15;
#pragma unroll
        for (int mt = 0; mt < MT; ++mt) {
            const float* rr = (const float*)&rn[mt];
#pragma unroll
            for (int r = 0; r < 4; ++r)
                Ms[(mt * 16 + rbase + r) * MP + fcol] = (__bf16)(acc[mt][ft][r] * rr[r]);
        }
    }
    __syncthreads();

    // ---- second GEMM: out[m][g] = sum_f msg[m][f] * W[g][f] ----
    fx4 acc2[MT][2] = {};
#pragma unroll
    for (int ks = 0; ks < 4; ++ks) {
        bf16x8 afm[MT];
#pragma unroll
        for (int mt = 0; mt < MT; ++mt)
            afm[mt] = *(const bf16x8*)&Ms[(mt * 16 + l15) * MP + ks * 32 + quad * 8];
#pragma unroll
        for (int gt = 0; gt < 2; ++gt) {
            int g = w * 32 + gt * 16 + l15;
            bf16x8 wfr = *(const bf16x8*)&Wb[(size_t)g * F_ + ks * 32 + quad * 8];
#pragma unroll
            for (int mt = 0; mt < MT; ++mt)
                acc2[mt][gt] = __builtin_amdgcn_mfma_f32_16x16x32_bf16(afm[mt], wfr, acc2[mt][gt], 0, 0, 0);
        }
    }

    // ---- bias + relu + store ----
#pragma unroll
    for (int gt = 0; gt < 2; ++gt) {
        int g = w * 32 + gt * 16 + l15;
        float bb = bias[g];
#pragma unroll
        for (int mt = 0; mt < MT; ++mt) {
#pragma unroll
            for (int r = 0; r < 4; ++r) {
                int e = e0 + mt * 16 + rbase + r;
                float v = acc2[mt][gt][r] + bb;
                out[((size_t)b * E_ + e) * F_ + g] = fmaxf(v, 0.f);
            }
        }
    }
}

extern "C" void kernel_launch(void* const* d_in, const int* in_sizes, int n_in,
                              void* d_out, int out_size, void* d_ws, size_t ws_size,
                              hipStream_t stream) {
    const float* node = (const float*)d_in[0];   // [B,N,F]
    const float* adj  = (const float*)d_in[1];   // [B,E,N]
    const float* W    = (const float*)d_in[2];   // [F,F]
    const float* bias = (const float*)d_in[3];   // [F]
    float* out = (float*)d_out;                  // [B,E,F]

    __bf16* nodeT = (__bf16*)d_ws;                               // 8 MB
    __bf16* Wb    = (__bf16*)((char*)d_ws + 8 * 1024 * 1024);    // 32 KB

    void* args[] = {(void*)&node, (void*)&adj, (void*)&W, (void*)&bias,
                    (void*)&nodeT, (void*)&Wb, (void*)&out};
    hipLaunchCooperativeKernel((const void*)v2h_coop, dim3(256), dim3(256),
                               args, 0, stream);
}